// Round 1
// baseline (220.570 us; speedup 1.0000x reference)
//
#include <hip/hip_runtime.h>

#define NUM_CLASSES 10

// One block per batch image, one wave (64 threads) per block.
// Thread t -> patch position (r, c) = (t>>3, t&7); sums 3 channels in double,
// wave-tree-reduces, lane 0 derives the class, lanes 0..9 write the one-hot.
__global__ __launch_bounds__(64) void ldc_kernel(const float* __restrict__ x,
                                                 float* __restrict__ out) {
    const int b = blockIdx.x;
    const int t = threadIdx.x;           // 0..63
    const int r = t >> 3;                // 0..7
    const int c = t & 7;                 // 0..7

    const size_t CH = 512ull * 512ull;   // channel stride
    const size_t base = (size_t)b * 3ull * CH + (size_t)r * 512ull + (size_t)c;

    // Sum the 3 channels for this (r,c) in double for accuracy.
    double s = (double)x[base] + (double)x[base + CH] + (double)x[base + 2 * CH];

    // Wave64 tree reduction (lane 0 ends with the total of all 192 elements).
    #pragma unroll
    for (int off = 32; off > 0; off >>= 1)
        s += __shfl_down(s, off, 64);

    int pred = 0;
    if (t == 0) {
        // Mirror reference float32 semantics: mean (fp32) * 10 -> trunc -> int32,
        // then Python-style non-negative mod 10.
        float mean = (float)(s / 192.0);
        float v = truncf(mean * 10.0f);
        int iv = (int)v;
        pred = iv % NUM_CLASSES;
        if (pred < 0) pred += NUM_CLASSES;
    }
    pred = __shfl(pred, 0, 64);

    if (t < NUM_CLASSES)
        out[b * NUM_CLASSES + t] = (t == pred) ? 10.0f : 0.0f;
}

extern "C" void kernel_launch(void* const* d_in, const int* in_sizes, int n_in,
                              void* d_out, int out_size, void* d_ws, size_t ws_size,
                              hipStream_t stream) {
    const float* x = (const float*)d_in[0];
    float* out = (float*)d_out;
    ldc_kernel<<<64, 64, 0, stream>>>(x, out);
}